// Round 1
// baseline (339.319 us; speedup 1.0000x reference)
//
#include <hip/hip_runtime.h>
#include <hip/hip_cooperative_groups.h>

namespace cg = cooperative_groups;

#define EPS 2e-5f

using short8  = __attribute__((ext_vector_type(8))) short;
using floatx4 = __attribute__((ext_vector_type(4))) float;

// round-to-nearest-even fp32 -> bf16 bits
static __device__ inline unsigned short f2bf(float f) {
    unsigned u = __float_as_uint(f);
    u += 0x7fffu + ((u >> 16) & 1u);
    return (unsigned short)(u >> 16);
}
static __device__ inline float bf2f(short s) {
    return __uint_as_float(((unsigned)(unsigned short)s) << 16);
}
static __device__ inline short8 scale8(short8 v, float sc) {
    short8 r;
    #pragma unroll
    for (int e = 0; e < 8; ++e) r[e] = (short)f2bf(bf2f(v[e]) * sc);
    return r;
}

// ---------------------------------------------------------------------------
// R9: single persistent cooperative kernel. The 5-kernel pipeline is
// latency/serialization-bound (each dispatch <42us; ideal traffic ~60MB=10us,
// MFMA ~18GF=8us). Fuse phases with grid.sync() instead of kernel boundaries;
// hoist tile-invariant work (k2 BN coeffs, k3 w3 staging + A-frags + bias).
// LDS phases overlaid in a union (max 59008B = k2) -> 2 blocks/CU -> 512
// co-resident blocks. Loop-top __syncthreads() covers LDS reuse across tiles
// (previously guaranteed by the kernel boundary). Fallback to the proven
// 5-kernel path if cooperative launch is unavailable.
// MFMA 16x16x32 bf16 layouts: A[m][k]: m=l&15, k=(l>>4)*8+e; B[k][n]: n=l&15;
// C/D: row=(l>>4)*4+r, col=l&15.
// ---------------------------------------------------------------------------

struct ShP1 {                       // phase 1 (conv1+pool+stats1)
    float z[32 * 276];
    float lsS[256], lsQ[256];
};
struct ShP2 {                       // phase 2 (bn1+conv2+pool+stats2)
    float z[32 * 260];
    unsigned short pt[4][64][40];
    float lsS[512], lsQ[512];
    float a1s[16], d1s[16], bias2L[256];
};
struct ShP3 {                       // phase 3 (bn2+conv3+pool+stats3)
    float w3s[6144];
    float a2s[32], d2s[32];
    unsigned short atile[32][72];
    float lsS[1024], lsQ[1024];
};
struct ShP4 {                       // phase 4 (bn3+FC head)
    float fw1L[5120];
    float a3s[64], d3s[64];
    unsigned short W1s[5120];
    float fw2s[256], fw3s[272], fb2s[16], fb3s[17], fb1f[16], tmp[4][16];
    float hbuf[4][16][17];
};
union ShU { ShP1 s1; ShP2 s2; ShP3 s3; ShP4 s4; };

__global__ void __launch_bounds__(256, 2)
fused(const float* __restrict__ x,  const float* __restrict__ w1,
      const float* __restrict__ w2, const float* __restrict__ w3,
      const float* __restrict__ g1, const float* __restrict__ b1,
      const float* __restrict__ g2, const float* __restrict__ b2,
      const float* __restrict__ g3, const float* __restrict__ b3,
      const float* __restrict__ fw1, const float* __restrict__ fb1,
      const float* __restrict__ fw2, const float* __restrict__ fb2,
      const float* __restrict__ fw3, const float* __restrict__ fb3,
      float* __restrict__ out,
      unsigned short* __restrict__ W1f, unsigned short* __restrict__ W2r,
      float* __restrict__ S,
      unsigned short* __restrict__ p1, unsigned short* __restrict__ p2s,
      unsigned short* __restrict__ act3, float* __restrict__ stats,
      float invN1, float invN2, float invN3, int B) {
    cg::grid_group gg = cg::this_grid();
    __shared__ ShU sh;
    const int tid = threadIdx.x;
    const int bid = blockIdx.x;
    const int G   = gridDim.x;
    float* stats1 = stats;
    float* stats2 = stats + 32;
    float* stats3 = stats + 96;

    // ---------------- phase S: weight staging + stats zero ----------------
    for (int gid = bid * 256 + tid; gid < 937984; gid += G * 256) {
        if (gid < 256) stats[gid] = 0.f;
        if (gid < 221184) {                  // W1f: 9*16*3*512
            int j  = gid / 24576;
            int r  = gid % 24576;
            int T  = r / 1536;
            int r2 = r % 1536;
            int ks = r2 / 512;
            int r3 = r2 % 512;
            int ln = r3 >> 3, e = r3 & 7;
            int n  = T * 16 + (ln & 15);
            int kk = ks * 32 + (ln >> 4) * 8 + e;
            int o = n >> 4, t = n & 15;
            int i = kk >> 4, s = kk & 15;
            int h = 1 << j;
            int d = s - t;
            float val = 0.f;
            if (d >= -3 * h && d <= 3 * h) {
                float df = (float)d / (float)h;
                #pragma unroll
                for (int m = 0; m < 7; ++m) {
                    float hat = fmaxf(0.f, 1.f - fabsf(df - (float)(m - 3)));
                    val += w1[(o * 6 + i) * 7 + m] * hat;
                }
                val /= (float)h;
            }
            W1f[gid] = f2bf(val);
        } else if (gid < 909312) {           // W2r: 7*16*12*512 raw frags
            int g  = gid - 221184;
            int fs = g >> 9;
            int ln = (g >> 3) & 63, e = g & 7;
            int j  = fs / 192;
            int rm = fs % 192;
            int T  = rm / 12, ks = rm % 12;
            int col = T * 16 + (ln & 15);
            int k   = ks * 32 + (ln >> 4) * 8 + e;
            int o = col >> 3, t = col & 7;
            int ic = k >> 3, s = k & 7;
            int i = ic / 3, c = ic % 3;
            int h = 1 << j;
            int d = s - t;
            float raw = 0.f;
            if (d >= -h && d <= h) {
                float df = (float)d / (float)h;
                #pragma unroll
                for (int m = 0; m < 3; ++m) {
                    float hat = fmaxf(0.f, 1.f - fabsf(df - (float)(m - 1)));
                    raw += w2[((o * 16 + i) * 3 + c) * 3 + m] * hat;
                }
                raw /= (float)h;
            }
            W2r[g] = f2bf(raw);
        } else {                             // S: 7*16*256 = sum_{c,s} raw
            int g = gid - 909312;
            int j = g >> 12;
            int r = g & 4095;
            int i = r >> 8;
            int col = r & 255;
            int o = col >> 3, t = col & 7;
            int h = 1 << j;
            float acc = 0.f;
            #pragma unroll
            for (int c = 0; c < 3; ++c) {
                const float* wr = &w2[((o * 16 + i) * 3 + c) * 3];
                #pragma unroll
                for (int s = 0; s < 8; ++s) {
                    int d = s - t;
                    if (d >= -h && d <= h) {
                        float df = (float)d / (float)h;
                        float raw = 0.f;
                        #pragma unroll
                        for (int m = 0; m < 3; ++m) {
                            float hat = fmaxf(0.f, 1.f - fabsf(df - (float)(m - 1)));
                            raw += wr[m] * hat;
                        }
                        acc += raw / (float)h;
                    }
                }
            }
            S[g] = acc;
        }
    }
    gg.sync();

    // ---------------- phase 1: conv1 + pool + relu + stats1 ----------------
    {
        const int wav = tid >> 6, lane = tid & 63;
        const int quad = lane >> 4, l15 = lane & 15;
        const int msub = wav & 1, nh = wav >> 1;
        const int nb1 = B / 32;              // 128
        for (int t = bid; t < nb1 * 9; t += G) {
            int j1 = t / nb1, bxx = t - j1 * nb1;
            int b0 = bxx * 32;
            __syncthreads();                 // LDS reuse across tiles
            floatx4 acc[8];
            #pragma unroll
            for (int T = 0; T < 8; ++T) acc[T] = floatx4{0.f, 0.f, 0.f, 0.f};
            const float* xr = x + (size_t)(b0 + msub * 16 + l15) * 96;
            const short8* Bj = (const short8*)W1f + (size_t)(j1 * 16) * 3 * 64;
            #pragma unroll
            for (int ks = 0; ks < 3; ++ks) {
                int k0 = ks * 32 + quad * 8;
                floatx4 v0 = *(const floatx4*)(xr + k0);
                floatx4 v1 = *(const floatx4*)(xr + k0 + 4);
                short8 a;
                #pragma unroll
                for (int e = 0; e < 4; ++e) {
                    a[e]     = (short)f2bf(v0[e]);
                    a[e + 4] = (short)f2bf(v1[e]);
                }
                #pragma unroll
                for (int T = 0; T < 8; ++T) {
                    short8 b = Bj[((nh * 8 + T) * 3 + ks) * 64 + lane];
                    acc[T] = __builtin_amdgcn_mfma_f32_16x16x32_bf16(a, b, acc[T], 0, 0, 0);
                }
            }
            #pragma unroll
            for (int T = 0; T < 8; ++T) {
                int col = (nh * 8 + T) * 16 + l15;
                int rb  = msub * 16 + quad * 4;
                #pragma unroll
                for (int r = 0; r < 4; ++r) sh.s1.z[(rb + r) * 276 + col] = acc[T][r];
            }
            __syncthreads();
            float psum = 0.f, pss = 0.f;
            #pragma unroll
            for (int i = 0; i < 2; ++i) {
                int u = tid + 256 * i;
                int row = u >> 4, o = u & 15;
                const float* zr = &sh.s1.z[row * 276 + o * 16];
                floatx4 q0 = ((const floatx4*)zr)[0];
                floatx4 q1 = ((const floatx4*)zr)[1];
                floatx4 q2 = ((const floatx4*)zr)[2];
                floatx4 q3 = ((const floatx4*)zr)[3];
                float tt[16] = {q0[0], q0[1], q0[2], q0[3], q1[0], q1[1], q1[2], q1[3],
                                q2[0], q2[1], q2[2], q2[3], q3[0], q3[1], q3[2], q3[3]};
                short8 pk;
                #pragma unroll
                for (int tp = 0; tp < 8; ++tp) {
                    int lo = (tp == 0) ? 0 : 2 * tp - 1;
                    int hi = (tp == 7) ? 15 : 2 * tp + 2;
                    float m = tt[lo];
                    for (int t2 = lo + 1; t2 <= hi; ++t2) m = fmaxf(m, tt[t2]);
                    m = fmaxf(m, 0.f);
                    pk[tp] = (short)f2bf(m);
                    psum += m; pss += m * m;
                }
                *(short8*)(p1 + ((size_t)j1 * B + b0 + row) * 128 + o * 8) = pk;
            }
            sh.s1.lsS[(tid & 15) * 16 + (tid >> 4)] = psum;
            sh.s1.lsQ[(tid & 15) * 16 + (tid >> 4)] = pss;
            __syncthreads();
            if (tid < 32) {
                int o = tid & 15;
                const float* src = (tid < 16) ? sh.s1.lsS : sh.s1.lsQ;
                float s = 0.f;
                #pragma unroll
                for (int g = 0; g < 16; ++g) s += src[o * 16 + g];
                atomicAdd(&stats1[(tid < 16 ? 0 : 16) + o], s);
            }
        }
    }
    gg.sync();

    // ---------------- phase 2: bn1 + conv2 + pool + relu + stats2 ----------
    {
        const int wav = tid >> 6, lane = tid & 63;
        const int quad = lane >> 4, l15 = lane & 15;
        const int nh = wav & 1, mp = wav >> 1;
        if (tid < 16) {                      // tile-invariant BN1 coefficients
            float mu  = stats1[tid] * invN1;
            float var = stats1[16 + tid] * invN1 - mu * mu;
            float rs  = rsqrtf(var + EPS);
            sh.s2.a1s[tid] = g1[tid] * rs;
            sh.s2.d1s[tid] = b1[tid] - mu * sh.s2.a1s[tid];
        }
        const int nb2 = B / 64;              // 64
        for (int t = bid; t < nb2 * 7; t += G) {
            int j2 = t / nb2, bxx = t - j2 * nb2;
            int b0 = bxx * 64, m0 = b0 + mp * 32;
            __syncthreads();                 // a1s/d1s visible; LDS reuse
            {   // bias2L[col] = sum_i d1[i]*S[j][i][col]
                float s = 0.f;
                const float* Sj = S + (size_t)j2 * 4096;
                #pragma unroll
                for (int i = 0; i < 16; ++i) s = fmaf(sh.s2.d1s[i], Sj[i * 256 + tid], s);
                sh.s2.bias2L[tid] = s;
            }
            __syncthreads();                 // bias2L read cross-thread below
            float biasv[8];
            #pragma unroll
            for (int T = 0; T < 8; ++T) biasv[T] = sh.s2.bias2L[(nh * 8 + T) * 16 + l15];
            floatx4 acc[2][8];
            #pragma unroll
            for (int mi = 0; mi < 2; ++mi)
                #pragma unroll
                for (int T = 0; T < 8; ++T) acc[mi][T] = floatx4{0.f, 0.f, 0.f, 0.f};
            const short8* Bj = (const short8*)W2r + (size_t)(j2 * 16) * 12 * 64;
            #pragma unroll
            for (int ks = 0; ks < 12; ++ks) {
                int icq = ks * 4 + quad;
                int i = icq / 3, c = icq - i * 3;
                float a1v = sh.s2.a1s[i];
                const unsigned short* ap = p1 + ((size_t)(j2 + c) * B + m0 + l15) * 128 + i * 8;
                short8 a0 = scale8(*(const short8*)ap, a1v);
                short8 a1 = scale8(*(const short8*)(ap + 2048), a1v);
                #pragma unroll
                for (int T = 0; T < 8; ++T) {
                    short8 b = Bj[((nh * 8 + T) * 12 + ks) * 64 + lane];
                    acc[0][T] = __builtin_amdgcn_mfma_f32_16x16x32_bf16(a0, b, acc[0][T], 0, 0, 0);
                    acc[1][T] = __builtin_amdgcn_mfma_f32_16x16x32_bf16(a1, b, acc[1][T], 0, 0, 0);
                }
            }
            float psum[2] = {0.f, 0.f}, pss[2] = {0.f, 0.f};
            for (int pass = 0; pass < 2; ++pass) {
                __syncthreads();
                if (mp == pass) {
                    #pragma unroll
                    for (int T = 0; T < 8; ++T) {
                        int col = (nh * 8 + T) * 16 + l15;
                        #pragma unroll
                        for (int mi = 0; mi < 2; ++mi) {
                            int rb = mi * 16 + quad * 4;
                            #pragma unroll
                            for (int r = 0; r < 4; ++r)
                                sh.s2.z[(rb + r) * 260 + col] = acc[mi][T][r] + biasv[T];
                        }
                    }
                }
                __syncthreads();
                #pragma unroll
                for (int i2 = 0; i2 < 2; ++i2) {
                    int u = tid + 256 * i2;
                    int opr = u & 15, row = u >> 4;
                    const float* zr = &sh.s2.z[row * 260 + opr * 16];
                    floatx4 q0 = ((const floatx4*)zr)[0];
                    floatx4 q1 = ((const floatx4*)zr)[1];
                    floatx4 q2 = ((const floatx4*)zr)[2];
                    floatx4 q3 = ((const floatx4*)zr)[3];
                    float ta[8] = {q0[0], q0[1], q0[2], q0[3], q1[0], q1[1], q1[2], q1[3]};
                    float tb[8] = {q2[0], q2[1], q2[2], q2[3], q3[0], q3[1], q3[2], q3[3]};
                    int rowg = pass * 32 + row;
                    #pragma unroll
                    for (int tp = 0; tp < 4; ++tp) {
                        int lo = (tp == 0) ? 0 : 2 * tp - 1;
                        int hi = (tp == 3) ? 7 : 2 * tp + 2;
                        float m0v = ta[lo], m1v = tb[lo];
                        for (int t2 = lo + 1; t2 <= hi; ++t2) {
                            m0v = fmaxf(m0v, ta[t2]); m1v = fmaxf(m1v, tb[t2]);
                        }
                        m0v = fmaxf(m0v, 0.f); m1v = fmaxf(m1v, 0.f);
                        psum[0] += m0v; pss[0] += m0v * m0v;
                        psum[1] += m1v; pss[1] += m1v * m1v;
                        unsigned pk = (unsigned)f2bf(m0v) | ((unsigned)f2bf(m1v) << 16);
                        *(unsigned*)&sh.s2.pt[tp][rowg][opr * 2] = pk;
                    }
                }
            }
            {
                int o0 = 2 * (tid & 15), g = tid >> 4;
                sh.s2.lsS[o0 * 16 + g] = psum[0]; sh.s2.lsS[(o0 + 1) * 16 + g] = psum[1];
                sh.s2.lsQ[o0 * 16 + g] = pss[0];  sh.s2.lsQ[(o0 + 1) * 16 + g] = pss[1];
            }
            __syncthreads();
            #pragma unroll
            for (int tp = 0; tp < 4; ++tp) {
                int oct = tid & 3, row = (tid >> 2) & 63;
                *(short8*)(p2s + ((size_t)(j2 * 4 + tp) * B + b0 + row) * 32 + oct * 8) =
                    *(const short8*)&sh.s2.pt[tp][row][oct * 8];
            }
            if (tid < 64) {
                int o = tid & 31;
                const float* src = (tid < 32) ? sh.s2.lsS : sh.s2.lsQ;
                float s = 0.f;
                #pragma unroll
                for (int g = 0; g < 16; ++g) s += src[o * 16 + g];
                atomicAdd(&stats2[(tid < 32 ? 0 : 32) + o], s);
            }
        }
    }
    gg.sync();

    // ---------------- phase 3: bn2 + conv3 + pool + relu + stats3 ----------
    {
        const int og = tid >> 6, lane = tid & 63;
        const int quad = lane >> 4, l15 = lane & 15;
        #pragma unroll
        for (int u = 0; u < 6; ++u) {        // tile-invariant: w3 staging
            int idx = tid * 4 + u * 1024;
            *(floatx4*)&sh.s3.w3s[idx] = *(const floatx4*)&w3[idx];
        }
        if (tid < 32) {                      // tile-invariant BN2 coefficients
            float mu  = stats2[tid] * invN2;
            float var = stats2[32 + tid] * invN2 - mu * mu;
            float rs  = rsqrtf(var + EPS);
            sh.s3.a2s[tid] = g2[tid] * rs;
            sh.s3.d2s[tid] = b2[tid] - mu * sh.s3.a2s[tid];
        }
        __syncthreads();
        int o = og * 16 + l15;
        float biasacc = 0.f;                 // tile-invariant A-frags + bias
        short8 af[3];
        #pragma unroll
        for (int kf = 0; kf < 3; ++kf) {
            short8 v;
            #pragma unroll
            for (int e = 0; e < 8; ++e) {
                int i = quad * 8 + e;
                float raw = sh.s3.w3s[o * 96 + i * 3 + kf];
                v[e] = (short)f2bf(raw * sh.s3.a2s[i]);
                biasacc = fmaf(raw, sh.s3.d2s[i], biasacc);
            }
            af[kf] = v;
        }
        biasacc += __shfl_xor(biasacc, 16, 64);
        biasacc += __shfl_xor(biasacc, 32, 64);
        float brow[4];
        #pragma unroll
        for (int r = 0; r < 4; ++r) brow[r] = __shfl(biasacc, quad * 4 + r, 64);
        const int nb3 = B / 32;              // 128
        for (int t = bid; t < nb3 * 5; t += G) {
            int j3 = t / nb3, bxx = t - j3 * nb3;
            int b0 = bxx * 32;
            float inv = 1.f / (float)(1 << j3);
            __syncthreads();                 // atile/lsS reuse across tiles
            float psum[4] = {0.f, 0.f, 0.f, 0.f}, pss[4] = {0.f, 0.f, 0.f, 0.f};
            #pragma unroll
            for (int bt = 0; bt < 2; ++bt) {
                int bb = b0 + bt * 16;
                floatx4 aL0 = {0.f, 0.f, 0.f, 0.f};
                floatx4 aL1 = {0.f, 0.f, 0.f, 0.f};
                floatx4 aL2 = {0.f, 0.f, 0.f, 0.f};
                #pragma unroll
                for (int c = 0; c < 3; ++c) {
                    const unsigned short* base =
                        p2s + ((size_t)((j3 + c) * 4) * B + bb + l15) * 32 + quad * 8;
                    short8 f0 = *(const short8*)base;
                    short8 f1 = *(const short8*)(base + (size_t)B * 32);
                    short8 f2v = *(const short8*)(base + (size_t)2 * B * 32);
                    aL0 = __builtin_amdgcn_mfma_f32_16x16x32_bf16(af[c], f0, aL0, 0, 0, 0);
                    aL1 = __builtin_amdgcn_mfma_f32_16x16x32_bf16(af[c], f1, aL1, 0, 0, 0);
                    aL2 = __builtin_amdgcn_mfma_f32_16x16x32_bf16(af[c], f2v, aL2, 0, 0, 0);
                }
                #pragma unroll
                for (int r = 0; r < 4; ++r) {
                    float vm = fmaxf(fmaxf(aL0[r], aL1[r]), aL2[r]);
                    float v  = fmaxf((vm + brow[r]) * inv, 0.f);
                    sh.s3.atile[bt * 16 + l15][og * 16 + quad * 4 + r] = f2bf(v);
                    psum[r] += v; pss[r] += v * v;
                }
            }
            #pragma unroll
            for (int r = 0; r < 4; ++r) {
                sh.s3.lsS[(og * 16 + quad * 4 + r) * 16 + l15] = psum[r];
                sh.s3.lsQ[(og * 16 + quad * 4 + r) * 16 + l15] = pss[r];
            }
            __syncthreads();
            {
                int row = tid >> 3, oct = tid & 7;
                *(short8*)(act3 + ((size_t)j3 * B + b0 + row) * 64 + oct * 8) =
                    *(const short8*)&sh.s3.atile[row][oct * 8];
            }
            if (tid < 128) {
                int oo = tid & 63;
                const float* src = (tid < 64) ? sh.s3.lsS : sh.s3.lsQ;
                float s = 0.f;
                #pragma unroll
                for (int g = 0; g < 16; ++g) s += src[oo * 16 + g];
                atomicAdd(&stats3[(tid < 64 ? 0 : 64) + oo], s);
            }
        }
    }
    gg.sync();

    // ---------------- phase 4: bn3 + FC head (needs B/64 blocks) ----------
    if (bid < B / 64) {
        const int wav = tid >> 6, lane = tid & 63;
        const int quad = lane >> 4, l15 = lane & 15;
        #pragma unroll
        for (int u = 0; u < 5; ++u) {        // coalesced fw1 preload (20 KB)
            int idx = (tid + u * 256) * 4;
            *(floatx4*)&sh.s4.fw1L[idx] = *(const floatx4*)&fw1[idx];
        }
        if (tid < 64) {
            float mu  = stats3[tid] * invN3;
            float var = stats3[64 + tid] * invN3 - mu * mu;
            float rs  = rsqrtf(var + EPS);
            sh.s4.a3s[tid] = g3[tid] * rs;
            sh.s4.d3s[tid] = b3[tid] - mu * sh.s4.a3s[tid];
        }
        if (tid < 16) sh.s4.fb2s[tid] = fb2[tid];
        if (tid < 17) sh.s4.fb3s[tid] = fb3[tid];
        sh.s4.fw2s[tid] = fw2[tid];
        for (int idx = tid; idx < 272; idx += 256) sh.s4.fw3s[idx] = fw3[idx];
        __syncthreads();
        #pragma unroll
        for (int u = 0; u < 20; ++u) {
            int idx = tid + u * 256;
            int e  = idx & 7;
            int ln = (idx >> 3) & 63;
            int fs = idx >> 9;
            int jj = fs >> 1, ks = fs & 1;
            int n = ln & 15;
            int oo = ks * 32 + (ln >> 4) * 8 + e;
            sh.s4.W1s[idx] = f2bf(sh.s4.fw1L[n * 320 + oo * 5 + jj] * sh.s4.a3s[oo]);
        }
        if (tid < 64) {
            int f = tid & 15, ch = tid >> 4;
            float s = 0.f;
            for (int u = 0; u < 80; ++u) {
                int n = ch * 80 + u;
                s = fmaf(sh.s4.fw1L[f * 320 + n], sh.s4.d3s[n / 5], s);
            }
            sh.s4.tmp[ch][f] = s;
        }
        __syncthreads();
        if (tid < 16) sh.s4.fb1f[tid] = fb1[tid] + sh.s4.tmp[0][tid] + sh.s4.tmp[1][tid]
                                      + sh.s4.tmp[2][tid] + sh.s4.tmp[3][tid];
        __syncthreads();
        int mt = bid * 4 + wav;              // 4 waves -> 4 row-tiles/block
        floatx4 acc = {0.f, 0.f, 0.f, 0.f};
        #pragma unroll
        for (int jj = 0; jj < 5; ++jj)
            #pragma unroll
            for (int ks = 0; ks < 2; ++ks) {
                short8 a = *(const short8*)(act3 +
                    ((size_t)jj * B + mt * 16 + l15) * 64 + ks * 32 + quad * 8);
                short8 b = *(const short8*)&sh.s4.W1s[((jj * 2 + ks) * 64 + lane) * 8];
                acc = __builtin_amdgcn_mfma_f32_16x16x32_bf16(a, b, acc, 0, 0, 0);
            }
        #pragma unroll
        for (int r = 0; r < 4; ++r)
            sh.s4.hbuf[wav][quad * 4 + r][l15] = acc[r] + sh.s4.fb1f[l15];
        __syncthreads();
        if (lane < 16) {
            int row = l15;
            float hv[16];
            #pragma unroll
            for (int n = 0; n < 16; ++n) hv[n] = sh.s4.hbuf[wav][row][n];
            float h2[16];
            #pragma unroll
            for (int f2 = 0; f2 < 16; ++f2) {
                float s = sh.s4.fb2s[f2];
                #pragma unroll
                for (int n = 0; n < 16; ++n) s = fmaf(sh.s4.fw2s[f2 * 16 + n], hv[n], s);
                h2[f2] = s;
            }
            float* orow = out + (size_t)(mt * 16 + row) * 17;
            #pragma unroll
            for (int f3 = 0; f3 < 17; ++f3) {
                float s = sh.s4.fb3s[f3];
                #pragma unroll
                for (int n = 0; n < 16; ++n) s = fmaf(sh.s4.fw3s[f3 * 16 + n], h2[n], s);
                orow[f3] = s;
            }
        }
    }
}

// ---------------------------------------------------------------------------
// Fallback: proven 5-kernel pipeline (identical to previous best, 173 us).
// ---------------------------------------------------------------------------

__global__ void __launch_bounds__(256) kS(const float* __restrict__ w1,
                                          const float* __restrict__ w2,
                                          unsigned short* __restrict__ W1f,
                                          unsigned short* __restrict__ W2r,
                                          float* __restrict__ S,
                                          float* __restrict__ stats) {
    int gid = blockIdx.x * 256 + threadIdx.x;
    if (gid < 256) stats[gid] = 0.f;
    if (gid < 221184) {
        int j  = gid / 24576;
        int r  = gid % 24576;
        int T  = r / 1536;
        int r2 = r % 1536;
        int ks = r2 / 512;
        int r3 = r2 % 512;
        int ln = r3 >> 3, e = r3 & 7;
        int n  = T * 16 + (ln & 15);
        int kk = ks * 32 + (ln >> 4) * 8 + e;
        int o = n >> 4, t = n & 15;
        int i = kk >> 4, s = kk & 15;
        int h = 1 << j;
        int d = s - t;
        float val = 0.f;
        if (d >= -3 * h && d <= 3 * h) {
            float df = (float)d / (float)h;
            #pragma unroll
            for (int m = 0; m < 7; ++m) {
                float hat = fmaxf(0.f, 1.f - fabsf(df - (float)(m - 3)));
                val += w1[(o * 6 + i) * 7 + m] * hat;
            }
            val /= (float)h;
        }
        W1f[gid] = f2bf(val);
    } else if (gid < 909312) {
        int g  = gid - 221184;
        int fs = g >> 9;
        int ln = (g >> 3) & 63, e = g & 7;
        int j  = fs / 192;
        int rm = fs % 192;
        int T  = rm / 12, ks = rm % 12;
        int col = T * 16 + (ln & 15);
        int k   = ks * 32 + (ln >> 4) * 8 + e;
        int o = col >> 3, t = col & 7;
        int ic = k >> 3, s = k & 7;
        int i = ic / 3, c = ic % 3;
        int h = 1 << j;
        int d = s - t;
        float raw = 0.f;
        if (d >= -h && d <= h) {
            float df = (float)d / (float)h;
            #pragma unroll
            for (int m = 0; m < 3; ++m) {
                float hat = fmaxf(0.f, 1.f - fabsf(df - (float)(m - 1)));
                raw += w2[((o * 16 + i) * 3 + c) * 3 + m] * hat;
            }
            raw /= (float)h;
        }
        W2r[g] = f2bf(raw);
    } else if (gid < 937984) {
        int g = gid - 909312;
        int j = g >> 12;
        int r = g & 4095;
        int i = r >> 8;
        int col = r & 255;
        int o = col >> 3, t = col & 7;
        int h = 1 << j;
        float acc = 0.f;
        #pragma unroll
        for (int c = 0; c < 3; ++c) {
            const float* wr = &w2[((o * 16 + i) * 3 + c) * 3];
            #pragma unroll
            for (int s = 0; s < 8; ++s) {
                int d = s - t;
                if (d >= -h && d <= h) {
                    float df = (float)d / (float)h;
                    float raw = 0.f;
                    #pragma unroll
                    for (int m = 0; m < 3; ++m) {
                        float hat = fmaxf(0.f, 1.f - fabsf(df - (float)(m - 1)));
                        raw += wr[m] * hat;
                    }
                    acc += raw / (float)h;
                }
            }
        }
        S[g] = acc;
    }
}

__global__ void __launch_bounds__(256) k1(const float* __restrict__ x,
                                          const unsigned short* __restrict__ W1f,
                                          unsigned short* __restrict__ p1,
                                          float* __restrict__ stats1, int B) {
    __shared__ float z[32 * 276];
    __shared__ float lsS[256], lsQ[256];
    int tid = threadIdx.x, j = blockIdx.y;
    int wav = tid >> 6, lane = tid & 63;
    int quad = lane >> 4, l15 = lane & 15;
    int msub = wav & 1, nh = wav >> 1;
    int b0 = blockIdx.x * 32;
    floatx4 acc[8];
    #pragma unroll
    for (int T = 0; T < 8; ++T) acc[T] = floatx4{0.f, 0.f, 0.f, 0.f};
    const float* xr = x + (size_t)(b0 + msub * 16 + l15) * 96;
    const short8* Bj = (const short8*)W1f + (size_t)(j * 16) * 3 * 64;
    #pragma unroll
    for (int ks = 0; ks < 3; ++ks) {
        int k0 = ks * 32 + quad * 8;
        floatx4 v0 = *(const floatx4*)(xr + k0);
        floatx4 v1 = *(const floatx4*)(xr + k0 + 4);
        short8 a;
        #pragma unroll
        for (int e = 0; e < 4; ++e) {
            a[e]     = (short)f2bf(v0[e]);
            a[e + 4] = (short)f2bf(v1[e]);
        }
        #pragma unroll
        for (int T = 0; T < 8; ++T) {
            short8 b = Bj[((nh * 8 + T) * 3 + ks) * 64 + lane];
            acc[T] = __builtin_amdgcn_mfma_f32_16x16x32_bf16(a, b, acc[T], 0, 0, 0);
        }
    }
    #pragma unroll
    for (int T = 0; T < 8; ++T) {
        int col = (nh * 8 + T) * 16 + l15;
        int rb  = msub * 16 + quad * 4;
        #pragma unroll
        for (int r = 0; r < 4; ++r) z[(rb + r) * 276 + col] = acc[T][r];
    }
    __syncthreads();
    float psum = 0.f, pss = 0.f;
    #pragma unroll
    for (int i = 0; i < 2; ++i) {
        int u = tid + 256 * i;
        int row = u >> 4, o = u & 15;
        const float* zr = &z[row * 276 + o * 16];
        floatx4 q0 = ((const floatx4*)zr)[0];
        floatx4 q1 = ((const floatx4*)zr)[1];
        floatx4 q2 = ((const floatx4*)zr)[2];
        floatx4 q3 = ((const floatx4*)zr)[3];
        float t[16] = {q0[0], q0[1], q0[2], q0[3], q1[0], q1[1], q1[2], q1[3],
                       q2[0], q2[1], q2[2], q2[3], q3[0], q3[1], q3[2], q3[3]};
        short8 pk;
        #pragma unroll
        for (int tp = 0; tp < 8; ++tp) {
            int lo = (tp == 0) ? 0 : 2 * tp - 1;
            int hi = (tp == 7) ? 15 : 2 * tp + 2;
            float m = t[lo];
            for (int tt = lo + 1; tt <= hi; ++tt) m = fmaxf(m, t[tt]);
            m = fmaxf(m, 0.f);
            pk[tp] = (short)f2bf(m);
            psum += m; pss += m * m;
        }
        *(short8*)(p1 + ((size_t)j * B + b0 + row) * 128 + o * 8) = pk;
    }
    lsS[(tid & 15) * 16 + (tid >> 4)] = psum;
    lsQ[(tid & 15) * 16 + (tid >> 4)] = pss;
    __syncthreads();
    if (tid < 32) {
        int o = tid & 15;
        const float* src = (tid < 16) ? lsS : lsQ;
        float s = 0.f;
        #pragma unroll
        for (int g = 0; g < 16; ++g) s += src[o * 16 + g];
        atomicAdd(&stats1[(tid < 16 ? 0 : 16) + o], s);
    }
}

__global__ void __launch_bounds__(256) k2(const unsigned short* __restrict__ p1,
                                          const unsigned short* __restrict__ W2r,
                                          const float* __restrict__ S,
                                          const float* __restrict__ g1,
                                          const float* __restrict__ b1,
                                          const float* __restrict__ stats1,
                                          unsigned short* __restrict__ p2s,
                                          float* __restrict__ stats2,
                                          float invN1, int B) {
    __shared__ float z[32 * 260];
    __shared__ unsigned short pt[4][64][40];
    __shared__ float lsS[512], lsQ[512];
    __shared__ float a1s[16], d1s[16], bias2L[256];
    int tid = threadIdx.x, j = blockIdx.y;
    int wav = tid >> 6, lane = tid & 63;
    int quad = lane >> 4, l15 = lane & 15;
    int nh = wav & 1, mp = wav >> 1;
    int b0 = blockIdx.x * 64, m0 = b0 + mp * 32;
    if (tid < 16) {
        float mu  = stats1[tid] * invN1;
        float var = stats1[16 + tid] * invN1 - mu * mu;
        float rs  = rsqrtf(var + EPS);
        a1s[tid] = g1[tid] * rs;
        d1s[tid] = b1[tid] - mu * a1s[tid];
    }
    __syncthreads();
    {
        float s = 0.f;
        const float* Sj = S + (size_t)j * 4096;
        #pragma unroll
        for (int i = 0; i < 16; ++i) s = fmaf(d1s[i], Sj[i * 256 + tid], s);
        bias2L[tid] = s;
    }
    __syncthreads();
    float biasv[8];
    #pragma unroll
    for (int T = 0; T < 8; ++T) biasv[T] = bias2L[(nh * 8 + T) * 16 + l15];
    floatx4 acc[2][8];
    #pragma unroll
    for (int mi = 0; mi < 2; ++mi)
        #pragma unroll
        for (int T = 0; T < 8; ++T) acc[mi][T] = floatx4{0.f, 0.f, 0.f, 0.f};
    const short8* Bj = (const short8*)W2r + (size_t)(j * 16) * 12 * 64;
    #pragma unroll
    for (int ks = 0; ks < 12; ++ks) {
        int icq = ks * 4 + quad;
        int i = icq / 3, c = icq - i * 3;
        float a1v = a1s[i];
        const unsigned short* ap = p1 + ((size_t)(j + c) * B + m0 + l15) * 128 + i * 8;
        short8 a0 = scale8(*(const short8*)ap, a1v);
        short8 a1 = scale8(*(const short8*)(ap + 2048), a1v);
        #pragma unroll
        for (int T = 0; T < 8; ++T) {
            short8 b = Bj[((nh * 8 + T) * 12 + ks) * 64 + lane];
            acc[0][T] = __builtin_amdgcn_mfma_f32_16x16x32_bf16(a0, b, acc[0][T], 0, 0, 0);
            acc[1][T] = __builtin_amdgcn_mfma_f32_16x16x32_bf16(a1, b, acc[1][T], 0, 0, 0);
        }
    }
    float psum[2] = {0.f, 0.f}, pss[2] = {0.f, 0.f};
    for (int pass = 0; pass < 2; ++pass) {
        __syncthreads();
        if (mp == pass) {
            #pragma unroll
            for (int T = 0; T < 8; ++T) {
                int col = (nh * 8 + T) * 16 + l15;
                #pragma unroll
                for (int mi = 0; mi < 2; ++mi) {
                    int rb = mi * 16 + quad * 4;
                    #pragma unroll
                    for (int r = 0; r < 4; ++r)
                        z[(rb + r) * 260 + col] = acc[mi][T][r] + biasv[T];
                }
            }
        }
        __syncthreads();
        #pragma unroll
        for (int i2 = 0; i2 < 2; ++i2) {
            int u = tid + 256 * i2;
            int opr = u & 15, row = u >> 4;
            const float* zr = &z[row * 260 + opr * 16];
            floatx4 q0 = ((const floatx4*)zr)[0];
            floatx4 q1 = ((const floatx4*)zr)[1];
            floatx4 q2 = ((const floatx4*)zr)[2];
            floatx4 q3 = ((const floatx4*)zr)[3];
            float ta[8] = {q0[0], q0[1], q0[2], q0[3], q1[0], q1[1], q1[2], q1[3]};
            float tb[8] = {q2[0], q2[1], q2[2], q2[3], q3[0], q3[1], q3[2], q3[3]};
            int rowg = pass * 32 + row;
            #pragma unroll
            for (int tp = 0; tp < 4; ++tp) {
                int lo = (tp == 0) ? 0 : 2 * tp - 1;
                int hi = (tp == 3) ? 7 : 2 * tp + 2;
                float m0v = ta[lo], m1v = tb[lo];
                for (int tt = lo + 1; tt <= hi; ++tt) {
                    m0v = fmaxf(m0v, ta[tt]); m1v = fmaxf(m1v, tb[tt]);
                }
                m0v = fmaxf(m0v, 0.f); m1v = fmaxf(m1v, 0.f);
                psum[0] += m0v; pss[0] += m0v * m0v;
                psum[1] += m1v; pss[1] += m1v * m1v;
                unsigned pk = (unsigned)f2bf(m0v) | ((unsigned)f2bf(m1v) << 16);
                *(unsigned*)&pt[tp][rowg][opr * 2] = pk;
            }
        }
    }
    {
        int o0 = 2 * (tid & 15), g = tid >> 4;
        lsS[o0 * 16 + g] = psum[0]; lsS[(o0 + 1) * 16 + g] = psum[1];
        lsQ[o0 * 16 + g] = pss[0];  lsQ[(o0 + 1) * 16 + g] = pss[1];
    }
    __syncthreads();
    #pragma unroll
    for (int tp = 0; tp < 4; ++tp) {
        int oct = tid & 3, row = (tid >> 2) & 63;
        *(short8*)(p2s + ((size_t)(j * 4 + tp) * B + b0 + row) * 32 + oct * 8) =
            *(const short8*)&pt[tp][row][oct * 8];
    }
    if (tid < 64) {
        int o = tid & 31;
        const float* src = (tid < 32) ? lsS : lsQ;
        float s = 0.f;
        #pragma unroll
        for (int g = 0; g < 16; ++g) s += src[o * 16 + g];
        atomicAdd(&stats2[(tid < 32 ? 0 : 32) + o], s);
    }
}

__global__ void __launch_bounds__(256) k3(const unsigned short* __restrict__ p2s,
                                          const float* __restrict__ w3,
                                          const float* __restrict__ g2,
                                          const float* __restrict__ b2,
                                          const float* __restrict__ stats2,
                                          unsigned short* __restrict__ act3,
                                          float* __restrict__ stats3,
                                          float invN2, int B) {
    __shared__ float w3s[6144];
    __shared__ float a2s[32], d2s[32];
    __shared__ unsigned short atile[32][72];
    __shared__ float lsS[1024], lsQ[1024];
    int tid = threadIdx.x, j = blockIdx.y, b0 = blockIdx.x * 32;
    int og = tid >> 6, lane = tid & 63;
    int quad = lane >> 4, l15 = lane & 15;
    #pragma unroll
    for (int u = 0; u < 6; ++u) {
        int idx = tid * 4 + u * 1024;
        *(floatx4*)&w3s[idx] = *(const floatx4*)&w3[idx];
    }
    if (tid < 32) {
        float mu  = stats2[tid] * invN2;
        float var = stats2[32 + tid] * invN2 - mu * mu;
        float rs  = rsqrtf(var + EPS);
        a2s[tid] = g2[tid] * rs;
        d2s[tid] = b2[tid] - mu * a2s[tid];
    }
    __syncthreads();
    int o = og * 16 + l15;
    float biasacc = 0.f;
    short8 af[3];
    #pragma unroll
    for (int kf = 0; kf < 3; ++kf) {
        short8 v;
        #pragma unroll
        for (int e = 0; e < 8; ++e) {
            int i = quad * 8 + e;
            float raw = w3s[o * 96 + i * 3 + kf];
            v[e] = (short)f2bf(raw * a2s[i]);
            biasacc = fmaf(raw, d2s[i], biasacc);
        }
        af[kf] = v;
    }
    biasacc += __shfl_xor(biasacc, 16, 64);
    biasacc += __shfl_xor(biasacc, 32, 64);
    float brow[4];
    #pragma unroll
    for (int r = 0; r < 4; ++r) brow[r] = __shfl(biasacc, quad * 4 + r, 64);
    float inv = 1.f / (float)(1 << j);
    float psum[4] = {0.f, 0.f, 0.f, 0.f}, pss[4] = {0.f, 0.f, 0.f, 0.f};
    #pragma unroll
    for (int bt = 0; bt < 2; ++bt) {
        int bb = b0 + bt * 16;
        floatx4 aL0 = {0.f, 0.f, 0.f, 0.f};
        floatx4 aL1 = {0.f, 0.f, 0.f, 0.f};
        floatx4 aL2 = {0.f, 0.f, 0.f, 0.f};
        #pragma unroll
        for (int c = 0; c < 3; ++c) {
            const unsigned short* base =
                p2s + ((size_t)((j + c) * 4) * B + bb + l15) * 32 + quad * 8;
            short8 f0 = *(const short8*)base;
            short8 f1 = *(const short8*)(base + (size_t)B * 32);
            short8 f2v = *(const short8*)(base + (size_t)2 * B * 32);
            aL0 = __builtin_amdgcn_mfma_f32_16x16x32_bf16(af[c], f0, aL0, 0, 0, 0);
            aL1 = __builtin_amdgcn_mfma_f32_16x16x32_bf16(af[c], f1, aL1, 0, 0, 0);
            aL2 = __builtin_amdgcn_mfma_f32_16x16x32_bf16(af[c], f2v, aL2, 0, 0, 0);
        }
        #pragma unroll
        for (int r = 0; r < 4; ++r) {
            float vm = fmaxf(fmaxf(aL0[r], aL1[r]), aL2[r]);
            float v  = fmaxf((vm + brow[r]) * inv, 0.f);
            atile[bt * 16 + l15][og * 16 + quad * 4 + r] = f2bf(v);
            psum[r] += v; pss[r] += v * v;
        }
    }
    #pragma unroll
    for (int r = 0; r < 4; ++r) {
        lsS[(og * 16 + quad * 4 + r) * 16 + l15] = psum[r];
        lsQ[(og * 16 + quad * 4 + r) * 16 + l15] = pss[r];
    }
    __syncthreads();
    {
        int row = tid >> 3, oct = tid & 7;
        *(short8*)(act3 + ((size_t)j * B + b0 + row) * 64 + oct * 8) =
            *(const short8*)&atile[row][oct * 8];
    }
    if (tid < 128) {
        int oo = tid & 63;
        const float* src = (tid < 64) ? lsS : lsQ;
        float s = 0.f;
        #pragma unroll
        for (int g = 0; g < 16; ++g) s += src[oo * 16 + g];
        atomicAdd(&stats3[(tid < 64 ? 0 : 64) + oo], s);
    }
}

__global__ void __launch_bounds__(128) k4(const unsigned short* __restrict__ act3,
                                          const float* __restrict__ g3,
                                          const float* __restrict__ b3,
                                          const float* __restrict__ stats3,
                                          const float* __restrict__ fw1,
                                          const float* __restrict__ fb1,
                                          const float* __restrict__ fw2,
                                          const float* __restrict__ fb2,
                                          const float* __restrict__ fw3,
                                          const float* __restrict__ fb3,
                                          float* __restrict__ out,
                                          float invN3, int B) {
    __shared__ float fw1L[5120];
    __shared__ float a3s[64], d3s[64];
    __shared__ unsigned short W1s[5120];
    __shared__ float fw2s[256], fw3s[272], fb2s[16], fb3s[17], fb1f[16], tmp[4][16];
    __shared__ float hbuf[2][16][17];
    int tid = threadIdx.x;
    int wav = tid >> 6, lane = tid & 63;
    int quad = lane >> 4, l15 = lane & 15;
    #pragma unroll
    for (int u = 0; u < 10; ++u) {
        int idx = (tid + u * 128) * 4;
        *(floatx4*)&fw1L[idx] = *(const floatx4*)&fw1[idx];
    }
    if (tid < 64) {
        float mu  = stats3[tid] * invN3;
        float var = stats3[64 + tid] * invN3 - mu * mu;
        float rs  = rsqrtf(var + EPS);
        a3s[tid] = g3[tid] * rs;
        d3s[tid] = b3[tid] - mu * a3s[tid];
    }
    if (tid < 16) fb2s[tid] = fb2[tid];
    if (tid < 17) fb3s[tid] = fb3[tid];
    #pragma unroll
    for (int u = 0; u < 2; ++u) fw2s[tid + u * 128] = fw2[tid + u * 128];
    for (int idx = tid; idx < 272; idx += 128) fw3s[idx] = fw3[idx];
    __syncthreads();
    #pragma unroll
    for (int u = 0; u < 40; ++u) {
        int idx = tid + u * 128;
        int e  = idx & 7;
        int ln = (idx >> 3) & 63;
        int fs = idx >> 9;
        int jj = fs >> 1, ks = fs & 1;
        int n = ln & 15;
        int oo = ks * 32 + (ln >> 4) * 8 + e;
        W1s[idx] = f2bf(fw1L[n * 320 + oo * 5 + jj] * a3s[oo]);
    }
    if (tid < 64) {
        int f = tid & 15, ch = tid >> 4;
        float s = 0.f;
        for (int u = 0; u < 80; ++u) {
            int n = ch * 80 + u;
            s = fmaf(fw1L[f * 320 + n], d3s[n / 5], s);
        }
        tmp[ch][f] = s;
    }
    __syncthreads();
    if (tid < 16) fb1f[tid] = fb1[tid] + tmp[0][tid] + tmp[1][tid] + tmp[2][tid] + tmp[3][tid];
    __syncthreads();
    int mt = blockIdx.x * 2 + wav;
    floatx4 acc = {0.f, 0.f, 0.f, 0.f};
    #pragma unroll
    for (int jj = 0; jj < 5; ++jj)
        #pragma unroll
        for (int ks = 0; ks < 2; ++ks) {
            short8 a = *(const short8*)(act3 +
                ((size_t)jj * B + mt * 16 + l15) * 64 + ks * 32 + quad * 8);
            short8 b = *(const short8*)&W1s[((jj * 2 + ks) * 64 + lane) * 8];
            acc = __builtin_amdgcn_mfma_f32_16x16x32_bf16(a, b, acc, 0, 0, 0);
        }
    #pragma unroll
    for (int r = 0; r < 4; ++r) hbuf[wav][quad * 4 + r][l15] = acc[r] + fb1f[l15];
    __syncthreads();
    if (lane < 16) {
        int row = l15;
        float hv[16];
        #pragma unroll
        for (int n = 0; n < 16; ++n) hv[n] = hbuf[wav][row][n];
        float h2[16];
        #pragma unroll
        for (int f2 = 0; f2 < 16; ++f2) {
            float s = fb2s[f2];
            #pragma unroll
            for (int n = 0; n < 16; ++n) s = fmaf(fw2s[f2 * 16 + n], hv[n], s);
            h2[f2] = s;
        }
        float* orow = out + (size_t)(mt * 16 + row) * 17;
        #pragma unroll
        for (int f3 = 0; f3 < 17; ++f3) {
            float s = fb3s[f3];
            #pragma unroll
            for (int n = 0; n < 16; ++n) s = fmaf(fw3s[f3 * 16 + n], h2[n], s);
            orow[f3] = s;
        }
    }
}

extern "C" void kernel_launch(void* const* d_in, const int* in_sizes, int n_in,
                              void* d_out, int out_size, void* d_ws, size_t ws_size,
                              hipStream_t stream) {
    (void)n_in; (void)out_size; (void)ws_size;
    const float* x   = (const float*)d_in[0];
    const float* w1  = (const float*)d_in[1];
    const float* w2  = (const float*)d_in[2];
    const float* w3  = (const float*)d_in[3];
    const float* g1  = (const float*)d_in[4];
    const float* b1  = (const float*)d_in[5];
    const float* g2  = (const float*)d_in[6];
    const float* b2  = (const float*)d_in[7];
    const float* g3  = (const float*)d_in[8];
    const float* b3  = (const float*)d_in[9];
    const float* fw1 = (const float*)d_in[10];
    const float* fb1 = (const float*)d_in[11];
    const float* fw2 = (const float*)d_in[12];
    const float* fb2 = (const float*)d_in[13];
    const float* fw3 = (const float*)d_in[14];
    const float* fb3 = (const float*)d_in[15];
    float* out = (float*)d_out;

    int B = in_sizes[0] / 96;                 // 4096

    char* wsb = (char*)d_ws;
    float*          stats = (float*)wsb;                      // 256 f
    unsigned short* W1f   = (unsigned short*)(wsb + 1024);    // 221184 us
    unsigned short* W2r   = W1f + 221184;                     // 688128 us
    float*          S     = (float*)(W2r + 688128);           // 28672 f
    unsigned short* p1    = (unsigned short*)(S + 28672);     // 9*B*128 us
    unsigned short* p2s   = p1 + (size_t)9 * B * 128;         // 28*B*32 us
    unsigned short* act3  = p2s + (size_t)28 * B * 32;        // 5*B*64 us

    float* stats1 = stats;
    float* stats2 = stats + 32;
    float* stats3 = stats + 96;

    float invN1 = 1.f / (float)(B * 72);
    float invN2 = 1.f / (float)(B * 28);
    float invN3 = 1.f / (float)(B * 5);

    // ---- cooperative fused path (cached occupancy; host-only queries) ----
    static int coopGrid = -2;                 // -2 uninit, -1 disabled, >0 grid
    if (coopGrid == -2) {
        int nb = 0;
        hipError_t e = hipOccupancyMaxActiveBlocksPerMultiprocessor(&nb, fused, 256, 0);
        if (e == hipSuccess && nb > 0) {
            long g = (long)nb * 256;          // 256 CUs on MI355X
            if (g > 1152) g = 1152;           // max tiles in any phase
            coopGrid = (int)g;
        } else {
            coopGrid = -1;
            (void)hipGetLastError();
        }
    }
    bool launched = false;
    if (coopGrid > 0) {
        void* args[] = {
            (void*)&x,   (void*)&w1,  (void*)&w2,  (void*)&w3,
            (void*)&g1,  (void*)&b1,  (void*)&g2,  (void*)&b2,
            (void*)&g3,  (void*)&b3,  (void*)&fw1, (void*)&fb1,
            (void*)&fw2, (void*)&fb2, (void*)&fw3, (void*)&fb3,
            (void*)&out, (void*)&W1f, (void*)&W2r, (void*)&S,
            (void*)&p1,  (void*)&p2s, (void*)&act3, (void*)&stats,
            (void*)&invN1, (void*)&invN2, (void*)&invN3, (void*)&B };
        hipError_t e = hipLaunchCooperativeKernel((const void*)fused, dim3(coopGrid),
                                                  dim3(256), args, 0, stream);
        if (e == hipSuccess) {
            launched = true;
        } else {
            coopGrid = -1;                    // never retry; fall back
            (void)hipGetLastError();
        }
    }
    if (!launched) {
        kS<<<3665, 256, 0, stream>>>(w1, w2, W1f, W2r, S, stats);
        k1<<<dim3(B / 32, 9), 256, 0, stream>>>(x, W1f, p1, stats1, B);
        k2<<<dim3(B / 64, 7), 256, 0, stream>>>(p1, W2r, S, g1, b1, stats1, p2s, stats2,
                                                invN1, B);
        k3<<<dim3(B / 32, 5), 256, 0, stream>>>(p2s, w3, g2, b2, stats2, act3, stats3,
                                                invN2, B);
        k4<<<B / 32, 128, 0, stream>>>(act3, g3, b3, stats3, fw1, fb1, fw2, fb2, fw3, fb3,
                                       out, invN3, B);
    }
}

// Round 2
// 174.394 us; speedup vs baseline: 1.9457x; 1.9457x over previous
//
#include <hip/hip_runtime.h>

#define EPS 2e-5f

using short8  = __attribute__((ext_vector_type(8))) short;
using floatx4 = __attribute__((ext_vector_type(4))) float;

// round-to-nearest-even fp32 -> bf16 bits
static __device__ inline unsigned short f2bf(float f) {
    unsigned u = __float_as_uint(f);
    u += 0x7fffu + ((u >> 16) & 1u);
    return (unsigned short)(u >> 16);
}
static __device__ inline float bf2f(short s) {
    return __uint_as_float(((unsigned)(unsigned short)s) << 16);
}
static __device__ inline short8 scale8(short8 v, float sc) {
    short8 r;
    #pragma unroll
    for (int e = 0; e < 8; ++e) r[e] = (short)f2bf(bf2f(v[e]) * sc);
    return r;
}

// ---------------------------------------------------------------------------
// R10: 5-dispatch latency attack (coop fused path REMOVED — R9 showed
// grid.sync costs ~a kernel boundary AND the LDS union halved occupancy).
// Changes vs 173us baseline:
//  - kSa: only W1f + stats zeroing (864 blocks, ~4us) stays on critical path.
//  - W2r/S staging folded into k1 as blockIdx.y==9 blocks (concurrent with
//    conv, off critical path).
//  - k2: pt[] LDS staging removed -> direct 4B packed stores to p2s.
//    LDS 59392->~38.5KB => 4 blocks/CU (was 2), one fewer barrier.
// MFMA 16x16x32 bf16 layouts: A[m][k]: m=l&15, k=(l>>4)*8+e; B[k][n]: n=l&15;
// C/D: row=(l>>4)*4+r, col=l&15.
// ---------------------------------------------------------------------------

__global__ void __launch_bounds__(256) kSa(const float* __restrict__ w1,
                                           unsigned short* __restrict__ W1f,
                                           float* __restrict__ stats) {
    int gid = blockIdx.x * 256 + threadIdx.x;   // grid 864*256 == 221184 exactly
    if (gid < 256) stats[gid] = 0.f;
    // W1f: 9*16*3*512
    int j  = gid / 24576;
    int r  = gid % 24576;
    int T  = r / 1536;
    int r2 = r % 1536;
    int ks = r2 / 512;
    int r3 = r2 % 512;
    int ln = r3 >> 3, e = r3 & 7;
    int n  = T * 16 + (ln & 15);
    int kk = ks * 32 + (ln >> 4) * 8 + e;
    int o = n >> 4, t = n & 15;
    int i = kk >> 4, s = kk & 15;
    int h = 1 << j;
    int d = s - t;
    float val = 0.f;
    if (d >= -3 * h && d <= 3 * h) {
        float df = (float)d / (float)h;
        #pragma unroll
        for (int m = 0; m < 7; ++m) {
            float hat = fmaxf(0.f, 1.f - fabsf(df - (float)(m - 3)));
            val += w1[(o * 6 + i) * 7 + m] * hat;
        }
        val /= (float)h;
    }
    W1f[gid] = f2bf(val);
}

__global__ void __launch_bounds__(256) k1(const float* __restrict__ x,
                                          const unsigned short* __restrict__ W1f,
                                          const float* __restrict__ w2,
                                          unsigned short* __restrict__ p1,
                                          unsigned short* __restrict__ W2r,
                                          float* __restrict__ S,
                                          float* __restrict__ stats1, int B) {
    __shared__ float z[32 * 276];            // stride 276: 2-way-free banks
    __shared__ float lsS[256], lsQ[256];
    int tid = threadIdx.x;

    if (blockIdx.y == 9) {                   // staging blocks: W2r + S for k2
        int base = blockIdx.x * 256 + tid;   // 0..32767 (128 x-blocks)
        for (int g = base; g < 688128; g += 32768) {   // W2r: 7*16*12*512
            int fs = g >> 9;                 // (j*16+T)*12+ks
            int ln = (g >> 3) & 63, e = g & 7;
            int j  = fs / 192;
            int rm = fs % 192;
            int T  = rm / 12, ks = rm % 12;
            int col = T * 16 + (ln & 15);
            int k   = ks * 32 + (ln >> 4) * 8 + e;
            int o = col >> 3, t = col & 7;
            int ic = k >> 3, s = k & 7;
            int i = ic / 3, c = ic % 3;
            int h = 1 << j;
            int d = s - t;
            float raw = 0.f;
            if (d >= -h && d <= h) {
                float df = (float)d / (float)h;
                #pragma unroll
                for (int m = 0; m < 3; ++m) {
                    float hat = fmaxf(0.f, 1.f - fabsf(df - (float)(m - 1)));
                    raw += w2[((o * 16 + i) * 3 + c) * 3 + m] * hat;
                }
                raw /= (float)h;
            }
            W2r[g] = f2bf(raw);
        }
        for (int g = base; g < 28672; g += 32768) {    // S: 7*16*256
            int j = g >> 12;
            int r = g & 4095;
            int i = r >> 8;
            int col = r & 255;
            int o = col >> 3, t = col & 7;
            int h = 1 << j;
            float acc = 0.f;
            #pragma unroll
            for (int c = 0; c < 3; ++c) {
                const float* wr = &w2[((o * 16 + i) * 3 + c) * 3];
                #pragma unroll
                for (int s = 0; s < 8; ++s) {
                    int d = s - t;
                    if (d >= -h && d <= h) {
                        float df = (float)d / (float)h;
                        float raw = 0.f;
                        #pragma unroll
                        for (int m = 0; m < 3; ++m) {
                            float hat = fmaxf(0.f, 1.f - fabsf(df - (float)(m - 1)));
                            raw += wr[m] * hat;
                        }
                        acc += raw / (float)h;
                    }
                }
            }
            S[g] = acc;
        }
        return;
    }

    int j = blockIdx.y;
    int wav = tid >> 6, lane = tid & 63;
    int quad = lane >> 4, l15 = lane & 15;
    int msub = wav & 1, nh = wav >> 1;
    int b0 = blockIdx.x * 32;
    floatx4 acc[8];
    #pragma unroll
    for (int T = 0; T < 8; ++T) acc[T] = floatx4{0.f, 0.f, 0.f, 0.f};
    const float* xr = x + (size_t)(b0 + msub * 16 + l15) * 96;
    const short8* Bj = (const short8*)W1f + (size_t)(j * 16) * 3 * 64;
    #pragma unroll
    for (int ks = 0; ks < 3; ++ks) {
        int k0 = ks * 32 + quad * 8;
        floatx4 v0 = *(const floatx4*)(xr + k0);
        floatx4 v1 = *(const floatx4*)(xr + k0 + 4);
        short8 a;
        #pragma unroll
        for (int e = 0; e < 4; ++e) {
            a[e]     = (short)f2bf(v0[e]);
            a[e + 4] = (short)f2bf(v1[e]);
        }
        #pragma unroll
        for (int T = 0; T < 8; ++T) {
            short8 b = Bj[((nh * 8 + T) * 3 + ks) * 64 + lane];
            acc[T] = __builtin_amdgcn_mfma_f32_16x16x32_bf16(a, b, acc[T], 0, 0, 0);
        }
    }
    #pragma unroll
    for (int T = 0; T < 8; ++T) {
        int col = (nh * 8 + T) * 16 + l15;
        int rb  = msub * 16 + quad * 4;
        #pragma unroll
        for (int r = 0; r < 4; ++r) z[(rb + r) * 276 + col] = acc[T][r];
    }
    __syncthreads();
    float psum = 0.f, pss = 0.f;
    #pragma unroll
    for (int i = 0; i < 2; ++i) {
        int u = tid + 256 * i;
        int row = u >> 4, o = u & 15;
        const float* zr = &z[row * 276 + o * 16];
        floatx4 q0 = ((const floatx4*)zr)[0];
        floatx4 q1 = ((const floatx4*)zr)[1];
        floatx4 q2 = ((const floatx4*)zr)[2];
        floatx4 q3 = ((const floatx4*)zr)[3];
        float t[16] = {q0[0], q0[1], q0[2], q0[3], q1[0], q1[1], q1[2], q1[3],
                       q2[0], q2[1], q2[2], q2[3], q3[0], q3[1], q3[2], q3[3]};
        short8 pk;
        #pragma unroll
        for (int tp = 0; tp < 8; ++tp) {
            int lo = (tp == 0) ? 0 : 2 * tp - 1;
            int hi = (tp == 7) ? 15 : 2 * tp + 2;
            float m = t[lo];
            for (int tt = lo + 1; tt <= hi; ++tt) m = fmaxf(m, t[tt]);
            m = fmaxf(m, 0.f);
            pk[tp] = (short)f2bf(m);
            psum += m; pss += m * m;
        }
        *(short8*)(p1 + ((size_t)j * B + b0 + row) * 128 + o * 8) = pk;
    }
    lsS[(tid & 15) * 16 + (tid >> 4)] = psum;
    lsQ[(tid & 15) * 16 + (tid >> 4)] = pss;
    __syncthreads();
    if (tid < 32) {
        int o = tid & 15;
        const float* src = (tid < 16) ? lsS : lsQ;
        float s = 0.f;
        #pragma unroll
        for (int g = 0; g < 16; ++g) s += src[o * 16 + g];
        atomicAdd(&stats1[(tid < 16 ? 0 : 16) + o], s);
    }
}

__global__ void __launch_bounds__(256) k2(const unsigned short* __restrict__ p1,
                                          const unsigned short* __restrict__ W2r,
                                          const float* __restrict__ S,
                                          const float* __restrict__ g1,
                                          const float* __restrict__ b1,
                                          const float* __restrict__ stats1,
                                          unsigned short* __restrict__ p2s,
                                          float* __restrict__ stats2,
                                          float invN1, int B) {
    __shared__ float z[32 * 260];
    __shared__ float lsS[512], lsQ[512];
    __shared__ float a1s[16], d1s[16], bias2L[256];
    int tid = threadIdx.x, j = blockIdx.y;
    int wav = tid >> 6, lane = tid & 63;
    int quad = lane >> 4, l15 = lane & 15;
    int nh = wav & 1, mp = wav >> 1;
    int b0 = blockIdx.x * 64, m0 = b0 + mp * 32;
    if (tid < 16) {
        float mu  = stats1[tid] * invN1;
        float var = stats1[16 + tid] * invN1 - mu * mu;
        float rs  = rsqrtf(var + EPS);
        a1s[tid] = g1[tid] * rs;
        d1s[tid] = b1[tid] - mu * a1s[tid];
    }
    __syncthreads();
    {   // bias2L[col] = sum_i d1[i]*S[j][i][col], coalesced over col=tid
        float s = 0.f;
        const float* Sj = S + (size_t)j * 4096;
        #pragma unroll
        for (int i = 0; i < 16; ++i) s = fmaf(d1s[i], Sj[i * 256 + tid], s);
        bias2L[tid] = s;
    }
    __syncthreads();                         // bias2L is read cross-thread below
    float biasv[8];
    #pragma unroll
    for (int T = 0; T < 8; ++T) biasv[T] = bias2L[(nh * 8 + T) * 16 + l15];
    floatx4 acc[2][8];
    #pragma unroll
    for (int mi = 0; mi < 2; ++mi)
        #pragma unroll
        for (int T = 0; T < 8; ++T) acc[mi][T] = floatx4{0.f, 0.f, 0.f, 0.f};
    const short8* Bj = (const short8*)W2r + (size_t)(j * 16) * 12 * 64;
    #pragma unroll
    for (int ks = 0; ks < 12; ++ks) {
        int icq = ks * 4 + quad;
        int i = icq / 3, c = icq - i * 3;
        float a1v = a1s[i];
        const unsigned short* ap = p1 + ((size_t)(j + c) * B + m0 + l15) * 128 + i * 8;
        short8 a0 = scale8(*(const short8*)ap, a1v);
        short8 a1 = scale8(*(const short8*)(ap + 2048), a1v);
        #pragma unroll
        for (int T = 0; T < 8; ++T) {
            short8 b = Bj[((nh * 8 + T) * 12 + ks) * 64 + lane];
            acc[0][T] = __builtin_amdgcn_mfma_f32_16x16x32_bf16(a0, b, acc[0][T], 0, 0, 0);
            acc[1][T] = __builtin_amdgcn_mfma_f32_16x16x32_bf16(a1, b, acc[1][T], 0, 0, 0);
        }
    }
    float psum[2] = {0.f, 0.f}, pss[2] = {0.f, 0.f};
    for (int pass = 0; pass < 2; ++pass) {
        __syncthreads();
        if (mp == pass) {
            #pragma unroll
            for (int T = 0; T < 8; ++T) {
                int col = (nh * 8 + T) * 16 + l15;
                #pragma unroll
                for (int mi = 0; mi < 2; ++mi) {
                    int rb = mi * 16 + quad * 4;
                    #pragma unroll
                    for (int r = 0; r < 4; ++r)
                        z[(rb + r) * 260 + col] = acc[mi][T][r] + biasv[T];
                }
            }
        }
        __syncthreads();
        #pragma unroll
        for (int i2 = 0; i2 < 2; ++i2) {
            int u = tid + 256 * i2;
            int opr = u & 15, row = u >> 4;
            const float* zr = &z[row * 260 + opr * 16];
            floatx4 q0 = ((const floatx4*)zr)[0];
            floatx4 q1 = ((const floatx4*)zr)[1];
            floatx4 q2 = ((const floatx4*)zr)[2];
            floatx4 q3 = ((const floatx4*)zr)[3];
            float ta[8] = {q0[0], q0[1], q0[2], q0[3], q1[0], q1[1], q1[2], q1[3]};
            float tb[8] = {q2[0], q2[1], q2[2], q2[3], q3[0], q3[1], q3[2], q3[3]};
            int rowg = pass * 32 + row;
            #pragma unroll
            for (int tp = 0; tp < 4; ++tp) {
                int lo = (tp == 0) ? 0 : 2 * tp - 1;
                int hi = (tp == 3) ? 7 : 2 * tp + 2;
                float m0v = ta[lo], m1v = tb[lo];
                for (int tt = lo + 1; tt <= hi; ++tt) {
                    m0v = fmaxf(m0v, ta[tt]); m1v = fmaxf(m1v, tb[tt]);
                }
                m0v = fmaxf(m0v, 0.f); m1v = fmaxf(m1v, 0.f);
                psum[0] += m0v; pss[0] += m0v * m0v;
                psum[1] += m1v; pss[1] += m1v * m1v;
                unsigned pk = (unsigned)f2bf(m0v) | ((unsigned)f2bf(m1v) << 16);
                // direct store (pt[] LDS staging removed): 4B per thread,
                // 16 threads cover 64B contiguous per (tp,rowg)
                *(unsigned*)(p2s + ((size_t)(j * 4 + tp) * B + b0 + rowg) * 32
                             + opr * 2) = pk;
            }
        }
    }
    {
        int o0 = 2 * (tid & 15), g = tid >> 4;
        lsS[o0 * 16 + g] = psum[0]; lsS[(o0 + 1) * 16 + g] = psum[1];
        lsQ[o0 * 16 + g] = pss[0];  lsQ[(o0 + 1) * 16 + g] = pss[1];
    }
    __syncthreads();
    if (tid < 64) {
        int o = tid & 31;
        const float* src = (tid < 32) ? lsS : lsQ;
        float s = 0.f;
        #pragma unroll
        for (int g = 0; g < 16; ++g) s += src[o * 16 + g];
        atomicAdd(&stats2[(tid < 32 ? 0 : 32) + o], s);
    }
}

__global__ void __launch_bounds__(256) k3(const unsigned short* __restrict__ p2s,
                                          const float* __restrict__ w3,
                                          const float* __restrict__ g2,
                                          const float* __restrict__ b2,
                                          const float* __restrict__ stats2,
                                          unsigned short* __restrict__ act3,
                                          float* __restrict__ stats3,
                                          float invN2, int B) {
    __shared__ float w3s[6144];
    __shared__ float a2s[32], d2s[32];
    __shared__ unsigned short atile[32][72];
    __shared__ float lsS[1024], lsQ[1024];
    int tid = threadIdx.x, j = blockIdx.y, b0 = blockIdx.x * 32;
    int og = tid >> 6, lane = tid & 63;
    int quad = lane >> 4, l15 = lane & 15;
    #pragma unroll
    for (int u = 0; u < 6; ++u) {            // coalesced preload (24 KB)
        int idx = tid * 4 + u * 1024;
        *(floatx4*)&w3s[idx] = *(const floatx4*)&w3[idx];
    }
    if (tid < 32) {
        float mu  = stats2[tid] * invN2;
        float var = stats2[32 + tid] * invN2 - mu * mu;
        float rs  = rsqrtf(var + EPS);
        a2s[tid] = g2[tid] * rs;
        d2s[tid] = b2[tid] - mu * a2s[tid];
    }
    __syncthreads();
    int o = og * 16 + l15;
    float biasacc = 0.f;
    short8 af[3];
    #pragma unroll
    for (int kf = 0; kf < 3; ++kf) {
        short8 v;
        #pragma unroll
        for (int e = 0; e < 8; ++e) {
            int i = quad * 8 + e;
            float raw = w3s[o * 96 + i * 3 + kf];
            v[e] = (short)f2bf(raw * a2s[i]);
            biasacc = fmaf(raw, d2s[i], biasacc);
        }
        af[kf] = v;
    }
    biasacc += __shfl_xor(biasacc, 16, 64);
    biasacc += __shfl_xor(biasacc, 32, 64);
    float brow[4];
    #pragma unroll
    for (int r = 0; r < 4; ++r) brow[r] = __shfl(biasacc, quad * 4 + r, 64);
    float inv = 1.f / (float)(1 << j);
    float psum[4] = {0.f, 0.f, 0.f, 0.f}, pss[4] = {0.f, 0.f, 0.f, 0.f};
    #pragma unroll
    for (int bt = 0; bt < 2; ++bt) {
        int bb = b0 + bt * 16;
        floatx4 aL0 = {0.f, 0.f, 0.f, 0.f};
        floatx4 aL1 = {0.f, 0.f, 0.f, 0.f};
        floatx4 aL2 = {0.f, 0.f, 0.f, 0.f};
        #pragma unroll
        for (int c = 0; c < 3; ++c) {
            const unsigned short* base =
                p2s + ((size_t)((j + c) * 4) * B + bb + l15) * 32 + quad * 8;
            short8 f0 = *(const short8*)base;
            short8 f1 = *(const short8*)(base + (size_t)B * 32);
            short8 f2v = *(const short8*)(base + (size_t)2 * B * 32);
            aL0 = __builtin_amdgcn_mfma_f32_16x16x32_bf16(af[c], f0, aL0, 0, 0, 0);
            aL1 = __builtin_amdgcn_mfma_f32_16x16x32_bf16(af[c], f1, aL1, 0, 0, 0);
            aL2 = __builtin_amdgcn_mfma_f32_16x16x32_bf16(af[c], f2v, aL2, 0, 0, 0);
        }
        #pragma unroll
        for (int r = 0; r < 4; ++r) {
            float vm = fmaxf(fmaxf(aL0[r], aL1[r]), aL2[r]);
            float v  = fmaxf((vm + brow[r]) * inv, 0.f);
            atile[bt * 16 + l15][og * 16 + quad * 4 + r] = f2bf(v);
            psum[r] += v; pss[r] += v * v;
        }
    }
    #pragma unroll
    for (int r = 0; r < 4; ++r) {
        lsS[(og * 16 + quad * 4 + r) * 16 + l15] = psum[r];
        lsQ[(og * 16 + quad * 4 + r) * 16 + l15] = pss[r];
    }
    __syncthreads();
    {
        int row = tid >> 3, oct = tid & 7;
        *(short8*)(act3 + ((size_t)j * B + b0 + row) * 64 + oct * 8) =
            *(const short8*)&atile[row][oct * 8];
    }
    if (tid < 128) {
        int oo = tid & 63;
        const float* src = (tid < 64) ? lsS : lsQ;
        float s = 0.f;
        #pragma unroll
        for (int g = 0; g < 16; ++g) s += src[oo * 16 + g];
        atomicAdd(&stats3[(tid < 64 ? 0 : 64) + oo], s);
    }
}

__global__ void __launch_bounds__(128) k4(const unsigned short* __restrict__ act3,
                                          const float* __restrict__ g3,
                                          const float* __restrict__ b3,
                                          const float* __restrict__ stats3,
                                          const float* __restrict__ fw1,
                                          const float* __restrict__ fb1,
                                          const float* __restrict__ fw2,
                                          const float* __restrict__ fb2,
                                          const float* __restrict__ fw3,
                                          const float* __restrict__ fb3,
                                          float* __restrict__ out,
                                          float invN3, int B) {
    __shared__ float fw1L[5120];
    __shared__ float a3s[64], d3s[64];
    __shared__ unsigned short W1s[5120];
    __shared__ float fw2s[256], fw3s[272], fb2s[16], fb3s[17], fb1f[16], tmp[4][16];
    __shared__ float hbuf[2][16][17];
    int tid = threadIdx.x;
    int wav = tid >> 6, lane = tid & 63;
    int quad = lane >> 4, l15 = lane & 15;
    #pragma unroll
    for (int u = 0; u < 10; ++u) {           // coalesced fw1 preload (20 KB)
        int idx = (tid + u * 128) * 4;
        *(floatx4*)&fw1L[idx] = *(const floatx4*)&fw1[idx];
    }
    if (tid < 64) {
        float mu  = stats3[tid] * invN3;
        float var = stats3[64 + tid] * invN3 - mu * mu;
        float rs  = rsqrtf(var + EPS);
        a3s[tid] = g3[tid] * rs;
        d3s[tid] = b3[tid] - mu * a3s[tid];
    }
    if (tid < 16) fb2s[tid] = fb2[tid];
    if (tid < 17) fb3s[tid] = fb3[tid];
    #pragma unroll
    for (int u = 0; u < 2; ++u) fw2s[tid + u * 128] = fw2[tid + u * 128];
    for (int idx = tid; idx < 272; idx += 128) fw3s[idx] = fw3[idx];
    __syncthreads();
    #pragma unroll
    for (int u = 0; u < 40; ++u) {
        int idx = tid + u * 128;
        int e  = idx & 7;
        int ln = (idx >> 3) & 63;
        int fs = idx >> 9;
        int jj = fs >> 1, ks = fs & 1;
        int n = ln & 15;
        int oo = ks * 32 + (ln >> 4) * 8 + e;
        W1s[idx] = f2bf(fw1L[n * 320 + oo * 5 + jj] * a3s[oo]);
    }
    if (tid < 64) {
        int f = tid & 15, ch = tid >> 4;
        float s = 0.f;
        for (int u = 0; u < 80; ++u) {
            int n = ch * 80 + u;
            s = fmaf(fw1L[f * 320 + n], d3s[n / 5], s);
        }
        tmp[ch][f] = s;
    }
    __syncthreads();
    if (tid < 16) fb1f[tid] = fb1[tid] + tmp[0][tid] + tmp[1][tid] + tmp[2][tid] + tmp[3][tid];
    __syncthreads();
    int mt = blockIdx.x * 2 + wav;
    floatx4 acc = {0.f, 0.f, 0.f, 0.f};
    #pragma unroll
    for (int jj = 0; jj < 5; ++jj)
        #pragma unroll
        for (int ks = 0; ks < 2; ++ks) {
            short8 a = *(const short8*)(act3 +
                ((size_t)jj * B + mt * 16 + l15) * 64 + ks * 32 + quad * 8);
            short8 b = *(const short8*)&W1s[((jj * 2 + ks) * 64 + lane) * 8];
            acc = __builtin_amdgcn_mfma_f32_16x16x32_bf16(a, b, acc, 0, 0, 0);
        }
    #pragma unroll
    for (int r = 0; r < 4; ++r) hbuf[wav][quad * 4 + r][l15] = acc[r] + fb1f[l15];
    __syncthreads();
    if (lane < 16) {
        int row = l15;
        float hv[16];
        #pragma unroll
        for (int n = 0; n < 16; ++n) hv[n] = hbuf[wav][row][n];
        float h2[16];
        #pragma unroll
        for (int f2 = 0; f2 < 16; ++f2) {
            float s = fb2s[f2];
            #pragma unroll
            for (int n = 0; n < 16; ++n) s = fmaf(fw2s[f2 * 16 + n], hv[n], s);
            h2[f2] = s;
        }
        float* orow = out + (size_t)(mt * 16 + row) * 17;
        #pragma unroll
        for (int f3 = 0; f3 < 17; ++f3) {
            float s = fb3s[f3];
            #pragma unroll
            for (int n = 0; n < 16; ++n) s = fmaf(fw3s[f3 * 16 + n], h2[n], s);
            orow[f3] = s;
        }
    }
}

extern "C" void kernel_launch(void* const* d_in, const int* in_sizes, int n_in,
                              void* d_out, int out_size, void* d_ws, size_t ws_size,
                              hipStream_t stream) {
    (void)n_in; (void)out_size; (void)ws_size;
    const float* x   = (const float*)d_in[0];
    const float* w1  = (const float*)d_in[1];
    const float* w2  = (const float*)d_in[2];
    const float* w3  = (const float*)d_in[3];
    const float* g1  = (const float*)d_in[4];
    const float* b1  = (const float*)d_in[5];
    const float* g2  = (const float*)d_in[6];
    const float* b2  = (const float*)d_in[7];
    const float* g3  = (const float*)d_in[8];
    const float* b3  = (const float*)d_in[9];
    const float* fw1 = (const float*)d_in[10];
    const float* fb1 = (const float*)d_in[11];
    const float* fw2 = (const float*)d_in[12];
    const float* fb2 = (const float*)d_in[13];
    const float* fw3 = (const float*)d_in[14];
    const float* fb3 = (const float*)d_in[15];
    float* out = (float*)d_out;

    int B = in_sizes[0] / 96;                 // 4096

    char* wsb = (char*)d_ws;
    float*          stats = (float*)wsb;                      // 256 f
    unsigned short* W1f   = (unsigned short*)(wsb + 1024);    // 221184 us
    unsigned short* W2r   = W1f + 221184;                     // 688128 us
    float*          S     = (float*)(W2r + 688128);           // 28672 f
    unsigned short* p1    = (unsigned short*)(S + 28672);     // 9*B*128 us
    unsigned short* p2s   = p1 + (size_t)9 * B * 128;         // 28*B*32 us
    unsigned short* act3  = p2s + (size_t)28 * B * 32;        // 5*B*64 us

    float* stats1 = stats;
    float* stats2 = stats + 32;
    float* stats3 = stats + 96;

    float invN1 = 1.f / (float)(B * 72);
    float invN2 = 1.f / (float)(B * 28);
    float invN3 = 1.f / (float)(B * 5);

    kSa<<<864, 256, 0, stream>>>(w1, W1f, stats);
    k1<<<dim3(B / 32, 10), 256, 0, stream>>>(x, W1f, w2, p1, W2r, S, stats1, B);
    k2<<<dim3(B / 64, 7), 256, 0, stream>>>(p1, W2r, S, g1, b1, stats1, p2s, stats2,
                                            invN1, B);
    k3<<<dim3(B / 32, 5), 256, 0, stream>>>(p2s, w3, g2, b2, stats2, act3, stats3,
                                            invN2, B);
    k4<<<B / 32, 128, 0, stream>>>(act3, g3, b3, stats3, fw1, fb1, fw2, fb2, fw3, fb3,
                                   out, invN3, B);
}